// Round 1
// baseline (5883.954 us; speedup 1.0000x reference)
//
#include <hip/hip_runtime.h>
#include <hip/hip_bf16.h>

constexpr int Nn = 100000;
constexpr int Ee = 1200000;
constexpr int Dd = 64;
constexpr int Ll = 5;
constexpr int Gg = 128;
constexpr int PDim = 320; // L*D

// ---------------------------------------------------------------------------
// GEMM: Y = act(X1 (+X2) @ W + b), X:(n,64), W:(64,64) row-major.
// Block = 256 threads, 64 rows per block. W staged in LDS (16KB),
// input tile staged TRANSPOSED in LDS (16KB) so each thread's 16-row
// read per k is 4x ds_read_b128 (wave-uniform broadcast).
// ---------------------------------------------------------------------------
template<bool ADD2, bool RELU>
__global__ __launch_bounds__(256) void gemm64(
    const float* __restrict__ X1, const float* __restrict__ X2,
    const float* __restrict__ W, const float* __restrict__ bias,
    float* __restrict__ Y, int nrows)
{
    __shared__ float Wl[64 * 64];
    __shared__ float inT[64 * 64]; // inT[k*64 + r]

    const int t = threadIdx.x;

    // stage W (4096 floats) coalesced as float4
    {
        const float4* Wv = (const float4*)W;
        float4* Wlv = (float4*)Wl;
        #pragma unroll
        for (int i = 0; i < 4; i++) Wlv[t + i * 256] = Wv[t + i * 256];
    }

    const int row0 = blockIdx.x * 64;
    {
        const int r = t & 63;          // row within tile
        const int row = row0 + r;
        const bool valid = row < nrows;
        #pragma unroll
        for (int i = 0; i < 4; i++) {
            const int k0 = ((t >> 6) * 4 + i) * 4; // 0..60 step 4
            float4 v = make_float4(0.f, 0.f, 0.f, 0.f);
            if (valid) {
                v = *(const float4*)(X1 + (size_t)row * 64 + k0);
                if constexpr (ADD2) {
                    float4 u = *(const float4*)(X2 + (size_t)row * 64 + k0);
                    v.x += u.x; v.y += u.y; v.z += u.z; v.w += u.w;
                }
            }
            inT[(k0 + 0) * 64 + r] = v.x;
            inT[(k0 + 1) * 64 + r] = v.y;
            inT[(k0 + 2) * 64 + r] = v.z;
            inT[(k0 + 3) * 64 + r] = v.w;
        }
    }
    __syncthreads();

    const int col = t & 63;
    const int rg = (t >> 6) * 16; // this thread's 16 rows
    float acc[16];
    #pragma unroll
    for (int j = 0; j < 16; j++) acc[j] = 0.f;

    #pragma unroll 4
    for (int k = 0; k < 64; k++) {
        const float w = Wl[k * 64 + col];
        const float4* ip = (const float4*)&inT[k * 64 + rg];
        const float4 a = ip[0], b = ip[1], c = ip[2], d = ip[3];
        acc[0]  = fmaf(a.x, w, acc[0]);
        acc[1]  = fmaf(a.y, w, acc[1]);
        acc[2]  = fmaf(a.z, w, acc[2]);
        acc[3]  = fmaf(a.w, w, acc[3]);
        acc[4]  = fmaf(b.x, w, acc[4]);
        acc[5]  = fmaf(b.y, w, acc[5]);
        acc[6]  = fmaf(b.z, w, acc[6]);
        acc[7]  = fmaf(b.w, w, acc[7]);
        acc[8]  = fmaf(c.x, w, acc[8]);
        acc[9]  = fmaf(c.y, w, acc[9]);
        acc[10] = fmaf(c.z, w, acc[10]);
        acc[11] = fmaf(c.w, w, acc[11]);
        acc[12] = fmaf(d.x, w, acc[12]);
        acc[13] = fmaf(d.y, w, acc[13]);
        acc[14] = fmaf(d.z, w, acc[14]);
        acc[15] = fmaf(d.w, w, acc[15]);
    }

    const float bb = bias[col];
    #pragma unroll
    for (int j = 0; j < 16; j++) {
        const int orow = row0 + rg + j;
        if (orow < nrows) {
            float v = acc[j] + bb;
            if constexpr (RELU) v = fmaxf(v, 0.f);
            Y[(size_t)orow * 64 + col] = v;
        }
    }
}

// ---------------------------------------------------------------------------
// Edge scatter: agg[dst] += h[src]. 16 threads per edge, float4 each.
// ---------------------------------------------------------------------------
__global__ __launch_bounds__(256) void scatter_agg(
    const int* __restrict__ ei, const float* __restrict__ h,
    float* __restrict__ agg)
{
    const long tid = (long)blockIdx.x * 256 + threadIdx.x;
    const int e = (int)(tid >> 4);
    if (e >= Ee) return;
    const int q = (int)(tid & 15);
    const int s = ei[e];
    const int d = ei[Ee + e];
    const float4 v = *(const float4*)(h + (size_t)s * 64 + q * 4);
    float* ap = agg + (size_t)d * 64 + q * 4;
    atomicAdd(ap + 0, v.x);
    atomicAdd(ap + 1, v.y);
    atomicAdd(ap + 2, v.z);
    atomicAdd(ap + 3, v.w);
}

// ---------------------------------------------------------------------------
// BatchNorm stats: per-column sum and sumsq over all rows (atomics into
// stats[0:64]=sum, stats[64:128]=sumsq).
// ---------------------------------------------------------------------------
__global__ __launch_bounds__(256) void bn_stats(
    const float* __restrict__ z, float* __restrict__ stats)
{
    const int t = threadIdx.x;
    const int col = t & 63;
    const int rg = t >> 6;
    float s = 0.f, s2 = 0.f;
    for (int row = blockIdx.x * 4 + rg; row < Nn; row += gridDim.x * 4) {
        const float v = z[(size_t)row * 64 + col];
        s += v;
        s2 += v * v;
    }
    __shared__ float red[4][64];
    red[rg][col] = s;
    __syncthreads();
    if (rg == 0) {
        const float tot = red[0][col] + red[1][col] + red[2][col] + red[3][col];
        atomicAdd(&stats[col], tot);
    }
    __syncthreads();
    red[rg][col] = s2;
    __syncthreads();
    if (rg == 0) {
        const float tot = red[0][col] + red[1][col] + red[2][col] + red[3][col];
        atomicAdd(&stats[64 + col], tot);
    }
}

// Compute scale/shift from stats, then zero stats for the next layer.
__global__ void bn_finalize(
    float* __restrict__ stats, const float* __restrict__ gamma,
    const float* __restrict__ beta, float* __restrict__ sc, int layer)
{
    const int c = threadIdx.x; // 64 threads, 1 block
    const float mean = stats[c] * (1.0f / Nn);
    const float var = stats[64 + c] * (1.0f / Nn) - mean * mean;
    const float scale = gamma[layer * 64 + c] * rsqrtf(var + 1e-5f);
    sc[c] = scale;
    sc[64 + c] = beta[layer * 64 + c] - mean * scale;
    stats[c] = 0.f;
    stats[64 + c] = 0.f;
}

__device__ inline int lower_bound_i(const int* __restrict__ a, int n, int v)
{
    int lo = 0, hi = n;
    while (lo < hi) {
        const int m = (lo + hi) >> 1;
        if (a[m] < v) lo = m + 1; else hi = m;
    }
    return lo;
}

// ---------------------------------------------------------------------------
// Apply BN in place and accumulate per-graph pooled sums (batch is sorted,
// one block per graph; no atomics).
// ---------------------------------------------------------------------------
__global__ __launch_bounds__(256) void bn_apply_pool(
    float* __restrict__ z, const int* __restrict__ batch,
    const float* __restrict__ sc, float* __restrict__ pooled, int layer)
{
    const int g = blockIdx.x;
    const int lo = lower_bound_i(batch, Nn, g);
    const int hi = lower_bound_i(batch, Nn, g + 1);
    const int t = threadIdx.x;
    const int col = t & 63;
    const int rg = t >> 6;
    const float scale = sc[col];
    const float shift = sc[64 + col];
    float acc = 0.f;
    for (int row = lo + rg; row < hi; row += 4) {
        float v = z[(size_t)row * 64 + col];
        v = fmaf(scale, v, shift);
        z[(size_t)row * 64 + col] = v;
        acc += v;
    }
    __shared__ float red[4][64];
    red[rg][col] = acc;
    __syncthreads();
    if (rg == 0) {
        pooled[g * PDim + layer * 64 + col] =
            red[0][col] + red[1][col] + red[2][col] + red[3][col];
    }
}

// ---------------------------------------------------------------------------
// Proj head GEMM: (128,320)@(320,320)+b. One thread per output element.
// ---------------------------------------------------------------------------
template<bool RELU>
__global__ __launch_bounds__(256) void proj(
    const float* __restrict__ X, const float* __restrict__ W,
    const float* __restrict__ bias, float* __restrict__ Y)
{
    const int idx = blockIdx.x * 256 + threadIdx.x; // grid*block == 40960 exact
    const int r = idx / PDim;
    const int c = idx - r * PDim;
    float acc = bias[c];
    #pragma unroll 8
    for (int k = 0; k < PDim; k++)
        acc = fmaf(X[r * PDim + k], W[k * PDim + c], acc);
    if constexpr (RELU) acc = fmaxf(acc, 0.f);
    Y[idx] = acc;
}

// ---------------------------------------------------------------------------
// Row-wise l2 normalize: out = v / max(||v||, 1e-12). One block (64) per row.
// ---------------------------------------------------------------------------
__global__ __launch_bounds__(64) void l2norm_rows(
    const float* __restrict__ X, float* __restrict__ out)
{
    const int r = blockIdx.x;
    const int l = threadIdx.x;
    float v[5];
    float s = 0.f;
    #pragma unroll
    for (int i = 0; i < 5; i++) {
        v[i] = X[r * PDim + i * 64 + l];
        s += v[i] * v[i];
    }
    #pragma unroll
    for (int off = 32; off > 0; off >>= 1) s += __shfl_down(s, off);
    s = __shfl(s, 0);
    const float d = fmaxf(sqrtf(s), 1e-12f);
    #pragma unroll
    for (int i = 0; i < 5; i++)
        out[r * PDim + i * 64 + l] = v[i] / d;
}

// ---------------------------------------------------------------------------
extern "C" void kernel_launch(void* const* d_in, const int* in_sizes, int n_in,
                              void* d_out, int out_size, void* d_ws, size_t ws_size,
                              hipStream_t stream)
{
    const float* x     = (const float*)d_in[0];
    const int*   ei    = (const int*)d_in[1];
    const int*   batch = (const int*)d_in[2];
    const float* Ws    = (const float*)d_in[3];
    const float* bs    = (const float*)d_in[4];
    const float* W1    = (const float*)d_in[5];
    const float* b1    = (const float*)d_in[6];
    const float* W2    = (const float*)d_in[7];
    const float* b2    = (const float*)d_in[8];
    const float* gamma = (const float*)d_in[9];
    const float* beta  = (const float*)d_in[10];
    const float* Wp1   = (const float*)d_in[11];
    const float* bp1   = (const float*)d_in[12];
    const float* Wp2   = (const float*)d_in[13];
    const float* bp2   = (const float*)d_in[14];
    float* out = (float*)d_out;

    float* A      = (float*)d_ws;                 // h        (N*64)
    float* B      = A + (size_t)Nn * 64;          // agg/z1/y (N*64)
    float* pooled = B + (size_t)Nn * 64;          // (G,320)
    float* ytmp   = pooled + (size_t)Gg * PDim;   // (G,320)
    float* stats  = ytmp + (size_t)Gg * PDim;     // 128 floats
    float* sc     = stats + 128;                  // 128 floats

    const int gemmGrid = (Nn + 63) / 64;
    const int scatGrid = (Ee * 16 + 255) / 256;

    hipMemsetAsync(stats, 0, 128 * sizeof(float), stream);

    // encoder: A = x @ Ws + bs
    gemm64<false, false><<<gemmGrid, 256, 0, stream>>>(x, nullptr, Ws, bs, A, Nn);

    for (int l = 0; l < Ll; l++) {
        hipMemsetAsync(B, 0, (size_t)Nn * 64 * sizeof(float), stream);
        scatter_agg<<<scatGrid, 256, 0, stream>>>(ei, A, B);
        // z1 = relu((A+B)@W1+b1) -> B   (each block writes only rows it staged)
        gemm64<true, true><<<gemmGrid, 256, 0, stream>>>(
            A, B, W1 + (size_t)l * 4096, b1 + (size_t)l * 64, B, Nn);
        // z2 = relu(B@W2+b2) -> A
        gemm64<false, true><<<gemmGrid, 256, 0, stream>>>(
            B, nullptr, W2 + (size_t)l * 4096, b2 + (size_t)l * 64, A, Nn);
        bn_stats<<<512, 256, 0, stream>>>(A, stats);
        bn_finalize<<<1, 64, 0, stream>>>(stats, gamma, beta, sc, l);
        bn_apply_pool<<<Gg, 256, 0, stream>>>(A, batch, sc, pooled, l);
    }

    // proj head
    proj<true><<<160, 256, 0, stream>>>(pooled, Wp1, bp1, ytmp);
    proj<false><<<160, 256, 0, stream>>>(ytmp, Wp2, bp2, B); // y -> B (free)

    l2norm_rows<<<Gg, 64, 0, stream>>>(B, out);                       // out0
    l2norm_rows<<<Gg, 64, 0, stream>>>(pooled, out + Gg * PDim);      // out1
}

// Round 2
// 1393.629 us; speedup vs baseline: 4.2220x; 4.2220x over previous
//
#include <hip/hip_runtime.h>
#include <hip/hip_bf16.h>

constexpr int Nn = 100000;
constexpr int Ee = 1200000;
constexpr int Dd = 64;
constexpr int Ll = 5;
constexpr int Gg = 128;
constexpr int PDim = 320; // L*D

// ---------------------------------------------------------------------------
// GEMM: Y = act(X1 (+X2) @ W + b), X:(n,64), W:(64,64) row-major.
// Block = 256 threads, 64 rows per block. W staged in LDS (16KB),
// input tile staged TRANSPOSED in LDS (16KB).
// ---------------------------------------------------------------------------
template<bool ADD2, bool RELU>
__global__ __launch_bounds__(256) void gemm64(
    const float* __restrict__ X1, const float* __restrict__ X2,
    const float* __restrict__ W, const float* __restrict__ bias,
    float* __restrict__ Y, int nrows)
{
    __shared__ float Wl[64 * 64];
    __shared__ float inT[64 * 64]; // inT[k*64 + r]

    const int t = threadIdx.x;

    // stage W (4096 floats) coalesced as float4
    {
        const float4* Wv = (const float4*)W;
        float4* Wlv = (float4*)Wl;
        #pragma unroll
        for (int i = 0; i < 4; i++) Wlv[t + i * 256] = Wv[t + i * 256];
    }

    const int row0 = blockIdx.x * 64;
    {
        const int r = t & 63;          // row within tile
        const int row = row0 + r;
        const bool valid = row < nrows;
        #pragma unroll
        for (int i = 0; i < 4; i++) {
            const int k0 = ((t >> 6) * 4 + i) * 4; // 0..60 step 4
            float4 v = make_float4(0.f, 0.f, 0.f, 0.f);
            if (valid) {
                v = *(const float4*)(X1 + (size_t)row * 64 + k0);
                if constexpr (ADD2) {
                    float4 u = *(const float4*)(X2 + (size_t)row * 64 + k0);
                    v.x += u.x; v.y += u.y; v.z += u.z; v.w += u.w;
                }
            }
            inT[(k0 + 0) * 64 + r] = v.x;
            inT[(k0 + 1) * 64 + r] = v.y;
            inT[(k0 + 2) * 64 + r] = v.z;
            inT[(k0 + 3) * 64 + r] = v.w;
        }
    }
    __syncthreads();

    const int col = t & 63;
    const int rg = (t >> 6) * 16; // this thread's 16 rows
    float acc[16];
    #pragma unroll
    for (int j = 0; j < 16; j++) acc[j] = 0.f;

    #pragma unroll 4
    for (int k = 0; k < 64; k++) {
        const float w = Wl[k * 64 + col];
        const float4* ip = (const float4*)&inT[k * 64 + rg];
        const float4 a = ip[0], b = ip[1], c = ip[2], d = ip[3];
        acc[0]  = fmaf(a.x, w, acc[0]);
        acc[1]  = fmaf(a.y, w, acc[1]);
        acc[2]  = fmaf(a.z, w, acc[2]);
        acc[3]  = fmaf(a.w, w, acc[3]);
        acc[4]  = fmaf(b.x, w, acc[4]);
        acc[5]  = fmaf(b.y, w, acc[5]);
        acc[6]  = fmaf(b.z, w, acc[6]);
        acc[7]  = fmaf(b.w, w, acc[7]);
        acc[8]  = fmaf(c.x, w, acc[8]);
        acc[9]  = fmaf(c.y, w, acc[9]);
        acc[10] = fmaf(c.z, w, acc[10]);
        acc[11] = fmaf(c.w, w, acc[11]);
        acc[12] = fmaf(d.x, w, acc[12]);
        acc[13] = fmaf(d.y, w, acc[13]);
        acc[14] = fmaf(d.z, w, acc[14]);
        acc[15] = fmaf(d.w, w, acc[15]);
    }

    const float bb = bias[col];
    #pragma unroll
    for (int j = 0; j < 16; j++) {
        const int orow = row0 + rg + j;
        if (orow < nrows) {
            float v = acc[j] + bb;
            if constexpr (RELU) v = fmaxf(v, 0.f);
            Y[(size_t)orow * 64 + col] = v;
        }
    }
}

// ---------------------------------------------------------------------------
// CSR build: degree count -> scan -> scatter-fill
// ---------------------------------------------------------------------------
__global__ __launch_bounds__(256) void count_deg(
    const int* __restrict__ ei, int* __restrict__ deg)
{
    const int e = blockIdx.x * 256 + threadIdx.x;
    if (e < Ee) atomicAdd(&deg[ei[Ee + e]], 1); // dst
}

// One block of 1024 threads: exclusive scan of deg[Nn] -> rowptr, cursor.
#define SCAN_T 1024
#define SCAN_CHUNK 98  // 1024*98 = 100352 >= Nn
__global__ __launch_bounds__(SCAN_T) void scan_deg(
    const int* __restrict__ deg, int* __restrict__ rowptr,
    int* __restrict__ cursor)
{
    const int t = threadIdx.x;
    const int beg = t * SCAN_CHUNK;
    const int end = min(beg + SCAN_CHUNK, Nn);
    int local = 0;
    for (int i = beg; i < end; i++) local += deg[i];

    __shared__ int sh[SCAN_T];
    sh[t] = local;
    __syncthreads();
    for (int off = 1; off < SCAN_T; off <<= 1) {
        int v = (t >= off) ? sh[t - off] : 0;
        __syncthreads();
        sh[t] += v;
        __syncthreads();
    }
    int run = (t == 0) ? 0 : sh[t - 1];
    for (int i = beg; i < end; i++) {
        rowptr[i] = run;
        cursor[i] = run;
        run += deg[i];
    }
    if (t == 0) rowptr[Nn] = Ee;
}

__global__ __launch_bounds__(256) void scatter_fill(
    const int* __restrict__ ei, int* __restrict__ cursor,
    int* __restrict__ col)
{
    const int e = blockIdx.x * 256 + threadIdx.x;
    if (e >= Ee) return;
    const int s = ei[e];
    const int d = ei[Ee + e];
    const int pos = atomicAdd(&cursor[d], 1);
    col[pos] = s;
}

// ---------------------------------------------------------------------------
// Pull aggregation: agg[r] = sum_{j in row r} h[col[j]].
// 16 lanes per row (float4 each), 16 rows per block.
// ---------------------------------------------------------------------------
__global__ __launch_bounds__(256) void gather_agg(
    const int* __restrict__ rowptr, const int* __restrict__ col,
    const float* __restrict__ h, float* __restrict__ agg)
{
    const int r = blockIdx.x * 16 + (threadIdx.x >> 4);
    if (r >= Nn) return;
    const int q = threadIdx.x & 15;
    const int beg = rowptr[r];
    const int end = rowptr[r + 1];
    float4 acc = make_float4(0.f, 0.f, 0.f, 0.f);
    for (int j = beg; j < end; j++) {
        const int s = col[j];
        const float4 v = *(const float4*)(h + (size_t)s * 64 + q * 4);
        acc.x += v.x; acc.y += v.y; acc.z += v.z; acc.w += v.w;
    }
    *(float4*)(agg + (size_t)r * 64 + q * 4) = acc;
}

// ---------------------------------------------------------------------------
// BatchNorm stats: per-column sum and sumsq over all rows.
// ---------------------------------------------------------------------------
__global__ __launch_bounds__(256) void bn_stats(
    const float* __restrict__ z, float* __restrict__ stats)
{
    const int t = threadIdx.x;
    const int col = t & 63;
    const int rg = t >> 6;
    float s = 0.f, s2 = 0.f;
    for (int row = blockIdx.x * 4 + rg; row < Nn; row += gridDim.x * 4) {
        const float v = z[(size_t)row * 64 + col];
        s += v;
        s2 += v * v;
    }
    __shared__ float red[4][64];
    red[rg][col] = s;
    __syncthreads();
    if (rg == 0) {
        const float tot = red[0][col] + red[1][col] + red[2][col] + red[3][col];
        atomicAdd(&stats[col], tot);
    }
    __syncthreads();
    red[rg][col] = s2;
    __syncthreads();
    if (rg == 0) {
        const float tot = red[0][col] + red[1][col] + red[2][col] + red[3][col];
        atomicAdd(&stats[64 + col], tot);
    }
}

// Compute scale/shift from stats, then zero stats for the next layer.
__global__ void bn_finalize(
    float* __restrict__ stats, const float* __restrict__ gamma,
    const float* __restrict__ beta, float* __restrict__ sc, int layer)
{
    const int c = threadIdx.x; // 64 threads, 1 block
    const float mean = stats[c] * (1.0f / Nn);
    const float var = stats[64 + c] * (1.0f / Nn) - mean * mean;
    const float scale = gamma[layer * 64 + c] * rsqrtf(var + 1e-5f);
    sc[c] = scale;
    sc[64 + c] = beta[layer * 64 + c] - mean * scale;
    stats[c] = 0.f;
    stats[64 + c] = 0.f;
}

__device__ inline int lower_bound_i(const int* __restrict__ a, int n, int v)
{
    int lo = 0, hi = n;
    while (lo < hi) {
        const int m = (lo + hi) >> 1;
        if (a[m] < v) lo = m + 1; else hi = m;
    }
    return lo;
}

// ---------------------------------------------------------------------------
// Apply BN in place and accumulate per-graph pooled sums (batch sorted).
// ---------------------------------------------------------------------------
__global__ __launch_bounds__(256) void bn_apply_pool(
    float* __restrict__ z, const int* __restrict__ batch,
    const float* __restrict__ sc, float* __restrict__ pooled, int layer)
{
    const int g = blockIdx.x;
    const int lo = lower_bound_i(batch, Nn, g);
    const int hi = lower_bound_i(batch, Nn, g + 1);
    const int t = threadIdx.x;
    const int col = t & 63;
    const int rg = t >> 6;
    const float scale = sc[col];
    const float shift = sc[64 + col];
    float acc = 0.f;
    for (int row = lo + rg; row < hi; row += 4) {
        float v = z[(size_t)row * 64 + col];
        v = fmaf(scale, v, shift);
        z[(size_t)row * 64 + col] = v;
        acc += v;
    }
    __shared__ float red[4][64];
    red[rg][col] = acc;
    __syncthreads();
    if (rg == 0) {
        pooled[g * PDim + layer * 64 + col] =
            red[0][col] + red[1][col] + red[2][col] + red[3][col];
    }
}

// ---------------------------------------------------------------------------
// Proj head GEMM: (128,320)@(320,320)+b. One thread per output element.
// ---------------------------------------------------------------------------
template<bool RELU>
__global__ __launch_bounds__(256) void proj(
    const float* __restrict__ X, const float* __restrict__ W,
    const float* __restrict__ bias, float* __restrict__ Y)
{
    const int idx = blockIdx.x * 256 + threadIdx.x; // 40960 exact
    const int r = idx / PDim;
    const int c = idx - r * PDim;
    float acc = bias[c];
    #pragma unroll 8
    for (int k = 0; k < PDim; k++)
        acc = fmaf(X[r * PDim + k], W[k * PDim + c], acc);
    if constexpr (RELU) acc = fmaxf(acc, 0.f);
    Y[idx] = acc;
}

// ---------------------------------------------------------------------------
// Row-wise l2 normalize.
// ---------------------------------------------------------------------------
__global__ __launch_bounds__(64) void l2norm_rows(
    const float* __restrict__ X, float* __restrict__ out)
{
    const int r = blockIdx.x;
    const int l = threadIdx.x;
    float v[5];
    float s = 0.f;
    #pragma unroll
    for (int i = 0; i < 5; i++) {
        v[i] = X[r * PDim + i * 64 + l];
        s += v[i] * v[i];
    }
    #pragma unroll
    for (int off = 32; off > 0; off >>= 1) s += __shfl_down(s, off);
    s = __shfl(s, 0);
    const float d = fmaxf(sqrtf(s), 1e-12f);
    #pragma unroll
    for (int i = 0; i < 5; i++)
        out[r * PDim + i * 64 + l] = v[i] / d;
}

// ---------------------------------------------------------------------------
extern "C" void kernel_launch(void* const* d_in, const int* in_sizes, int n_in,
                              void* d_out, int out_size, void* d_ws, size_t ws_size,
                              hipStream_t stream)
{
    const float* x     = (const float*)d_in[0];
    const int*   ei    = (const int*)d_in[1];
    const int*   batch = (const int*)d_in[2];
    const float* Ws    = (const float*)d_in[3];
    const float* bs    = (const float*)d_in[4];
    const float* W1    = (const float*)d_in[5];
    const float* b1    = (const float*)d_in[6];
    const float* W2    = (const float*)d_in[7];
    const float* b2    = (const float*)d_in[8];
    const float* gamma = (const float*)d_in[9];
    const float* beta  = (const float*)d_in[10];
    const float* Wp1   = (const float*)d_in[11];
    const float* bp1   = (const float*)d_in[12];
    const float* Wp2   = (const float*)d_in[13];
    const float* bp2   = (const float*)d_in[14];
    float* out = (float*)d_out;

    float* A      = (float*)d_ws;                 // h        (N*64)
    float* B      = A + (size_t)Nn * 64;          // agg/z1/y (N*64)
    float* pooled = B + (size_t)Nn * 64;          // (G,320)
    float* ytmp   = pooled + (size_t)Gg * PDim;   // (G,320)
    float* stats  = ytmp + (size_t)Gg * PDim;     // 128 floats
    float* sc     = stats + 128;                  // 128 floats
    int*   deg    = (int*)(sc + 128);             // N ints
    int*   rowptr = deg + Nn;                     // N+1 ints
    int*   cursor = rowptr + Nn + 1;              // N ints
    int*   colidx = cursor + Nn;                  // E ints

    const int gemmGrid = (Nn + 63) / 64;
    const int edgeGrid = (Ee + 255) / 256;

    hipMemsetAsync(stats, 0, 128 * sizeof(float), stream);
    hipMemsetAsync(deg, 0, Nn * sizeof(int), stream);

    // CSR build (once per launch)
    count_deg<<<edgeGrid, 256, 0, stream>>>(ei, deg);
    scan_deg<<<1, SCAN_T, 0, stream>>>(deg, rowptr, cursor);
    scatter_fill<<<edgeGrid, 256, 0, stream>>>(ei, cursor, colidx);

    // encoder: A = x @ Ws + bs
    gemm64<false, false><<<gemmGrid, 256, 0, stream>>>(x, nullptr, Ws, bs, A, Nn);

    for (int l = 0; l < Ll; l++) {
        gather_agg<<<(Nn + 15) / 16, 256, 0, stream>>>(rowptr, colidx, A, B);
        // z1 = relu((A+B)@W1+b1) -> B
        gemm64<true, true><<<gemmGrid, 256, 0, stream>>>(
            A, B, W1 + (size_t)l * 4096, b1 + (size_t)l * 64, B, Nn);
        // z2 = relu(B@W2+b2) -> A
        gemm64<false, true><<<gemmGrid, 256, 0, stream>>>(
            B, nullptr, W2 + (size_t)l * 4096, b2 + (size_t)l * 64, A, Nn);
        bn_stats<<<512, 256, 0, stream>>>(A, stats);
        bn_finalize<<<1, 64, 0, stream>>>(stats, gamma, beta, sc, l);
        bn_apply_pool<<<Gg, 256, 0, stream>>>(A, batch, sc, pooled, l);
    }

    // proj head
    proj<true><<<160, 256, 0, stream>>>(pooled, Wp1, bp1, ytmp);
    proj<false><<<160, 256, 0, stream>>>(ytmp, Wp2, bp2, B);

    l2norm_rows<<<Gg, 64, 0, stream>>>(B, out);                  // out0
    l2norm_rows<<<Gg, 64, 0, stream>>>(pooled, out + Gg * PDim); // out1
}

// Round 3
// 1015.453 us; speedup vs baseline: 5.7944x; 1.3724x over previous
//
#include <hip/hip_runtime.h>
#include <hip/hip_bf16.h>

constexpr int Nn = 100000;
constexpr int Ee = 1200000;
constexpr int Dd = 64;
constexpr int Ll = 5;
constexpr int Gg = 128;
constexpr int PDim = 320; // L*D

// ---------------------------------------------------------------------------
// GEMM: Y = act(X1 (+X2) @ W + b), X:(n,64), W:(64,64) row-major.
// Block = 256 threads, 64 rows per block. W staged in LDS (16KB),
// input tile staged TRANSPOSED in LDS (16KB).
// STATS: accumulate per-column sum/sumsq of the (post-activation) output
// into stats[0:64]/stats[64:128] via one atomic pair per column per block.
// ---------------------------------------------------------------------------
template<bool ADD2, bool RELU, bool STATS>
__global__ __launch_bounds__(256) void gemm64(
    const float* __restrict__ X1, const float* __restrict__ X2,
    const float* __restrict__ W, const float* __restrict__ bias,
    float* __restrict__ Y, float* __restrict__ stats, int nrows)
{
    __shared__ float Wl[64 * 64];
    __shared__ float inT[64 * 64]; // inT[k*64 + r]

    const int t = threadIdx.x;

    // stage W (4096 floats) coalesced as float4
    {
        const float4* Wv = (const float4*)W;
        float4* Wlv = (float4*)Wl;
        #pragma unroll
        for (int i = 0; i < 4; i++) Wlv[t + i * 256] = Wv[t + i * 256];
    }

    const int row0 = blockIdx.x * 64;
    {
        const int r = t & 63;          // row within tile
        const int row = row0 + r;
        const bool valid = row < nrows;
        #pragma unroll
        for (int i = 0; i < 4; i++) {
            const int k0 = ((t >> 6) * 4 + i) * 4; // 0..60 step 4
            float4 v = make_float4(0.f, 0.f, 0.f, 0.f);
            if (valid) {
                v = *(const float4*)(X1 + (size_t)row * 64 + k0);
                if constexpr (ADD2) {
                    float4 u = *(const float4*)(X2 + (size_t)row * 64 + k0);
                    v.x += u.x; v.y += u.y; v.z += u.z; v.w += u.w;
                }
            }
            inT[(k0 + 0) * 64 + r] = v.x;
            inT[(k0 + 1) * 64 + r] = v.y;
            inT[(k0 + 2) * 64 + r] = v.z;
            inT[(k0 + 3) * 64 + r] = v.w;
        }
    }
    __syncthreads();

    const int col = t & 63;
    const int rg = (t >> 6) * 16; // this thread's 16 rows
    float acc[16];
    #pragma unroll
    for (int j = 0; j < 16; j++) acc[j] = 0.f;

    #pragma unroll 4
    for (int k = 0; k < 64; k++) {
        const float w = Wl[k * 64 + col];
        const float4* ip = (const float4*)&inT[k * 64 + rg];
        const float4 a = ip[0], b = ip[1], c = ip[2], d = ip[3];
        acc[0]  = fmaf(a.x, w, acc[0]);
        acc[1]  = fmaf(a.y, w, acc[1]);
        acc[2]  = fmaf(a.z, w, acc[2]);
        acc[3]  = fmaf(a.w, w, acc[3]);
        acc[4]  = fmaf(b.x, w, acc[4]);
        acc[5]  = fmaf(b.y, w, acc[5]);
        acc[6]  = fmaf(b.z, w, acc[6]);
        acc[7]  = fmaf(b.w, w, acc[7]);
        acc[8]  = fmaf(c.x, w, acc[8]);
        acc[9]  = fmaf(c.y, w, acc[9]);
        acc[10] = fmaf(c.z, w, acc[10]);
        acc[11] = fmaf(c.w, w, acc[11]);
        acc[12] = fmaf(d.x, w, acc[12]);
        acc[13] = fmaf(d.y, w, acc[13]);
        acc[14] = fmaf(d.z, w, acc[14]);
        acc[15] = fmaf(d.w, w, acc[15]);
    }

    const float bb = bias[col];
    float s = 0.f, s2 = 0.f;
    #pragma unroll
    for (int j = 0; j < 16; j++) {
        const int orow = row0 + rg + j;
        if (orow < nrows) {
            float v = acc[j] + bb;
            if constexpr (RELU) v = fmaxf(v, 0.f);
            Y[(size_t)orow * 64 + col] = v;
            if constexpr (STATS) { s += v; s2 += v * v; }
        }
    }

    if constexpr (STATS) {
        // reduce the 4 row-groups per column, one atomic pair per column
        __syncthreads();                // done with inT
        float* red = inT;               // reuse LDS
        red[(t >> 6) * 64 + col] = s;
        red[256 + (t >> 6) * 64 + col] = s2;
        __syncthreads();
        if (t < 64) {
            const float ts  = red[t] + red[64 + t] + red[128 + t] + red[192 + t];
            const float ts2 = red[256 + t] + red[320 + t] + red[384 + t] + red[448 + t];
            atomicAdd(&stats[t], ts);
            atomicAdd(&stats[64 + t], ts2);
        }
    }
}

// ---------------------------------------------------------------------------
// CSR build: degree count -> device-wide scan (3 phases) -> scatter-fill
// ---------------------------------------------------------------------------
__global__ __launch_bounds__(256) void count_deg(
    const int* __restrict__ ei, int* __restrict__ deg)
{
    const int e = blockIdx.x * 256 + threadIdx.x;
    if (e < Ee) atomicAdd(&deg[ei[Ee + e]], 1); // dst
}

constexpr int SCAN_TILE = 1024;                       // 256 thr * 4
constexpr int SCAN_NBLK = (Nn + SCAN_TILE - 1) / SCAN_TILE; // 98

__global__ __launch_bounds__(256) void deg_block_reduce(
    const int* __restrict__ deg, int* __restrict__ blockSums)
{
    const int t = threadIdx.x;
    const int base = blockIdx.x * SCAN_TILE + t * 4;
    int s = 0;
    if (base + 4 <= Nn) {
        const int4 v = *(const int4*)(deg + base);
        s = v.x + v.y + v.z + v.w;
    } else {
        for (int i = 0; i < 4; i++) if (base + i < Nn) s += deg[base + i];
    }
    __shared__ int sh[256];
    sh[t] = s;
    __syncthreads();
    for (int off = 128; off > 0; off >>= 1) {
        if (t < off) sh[t] += sh[t + off];
        __syncthreads();
    }
    if (t == 0) blockSums[blockIdx.x] = sh[0];
}

__global__ __launch_bounds__(128) void scan_blocksums(
    int* __restrict__ blockSums)
{
    __shared__ int sh[128];
    const int t = threadIdx.x;
    const int v = (t < SCAN_NBLK) ? blockSums[t] : 0;
    sh[t] = v;
    __syncthreads();
    for (int off = 1; off < 128; off <<= 1) {
        const int u = (t >= off) ? sh[t - off] : 0;
        __syncthreads();
        sh[t] += u;
        __syncthreads();
    }
    if (t < SCAN_NBLK) blockSums[t] = sh[t] - v; // exclusive
}

__global__ __launch_bounds__(256) void deg_scan_scatter(
    const int* __restrict__ deg, const int* __restrict__ blockSums,
    int* __restrict__ rowptr, int* __restrict__ cursor)
{
    const int t = threadIdx.x;
    const int base = blockIdx.x * SCAN_TILE + t * 4;
    int v[4];
    int s = 0;
    #pragma unroll
    for (int i = 0; i < 4; i++) {
        const int idx = base + i;
        v[i] = (idx < Nn) ? deg[idx] : 0;
        s += v[i];
    }
    __shared__ int sh[256];
    sh[t] = s;
    __syncthreads();
    for (int off = 1; off < 256; off <<= 1) {
        const int u = (t >= off) ? sh[t - off] : 0;
        __syncthreads();
        sh[t] += u;
        __syncthreads();
    }
    int excl = sh[t] - s + blockSums[blockIdx.x];
    #pragma unroll
    for (int i = 0; i < 4; i++) {
        const int idx = base + i;
        if (idx < Nn) {
            rowptr[idx] = excl;
            cursor[idx] = excl;
            excl += v[i];
        }
    }
    if (blockIdx.x == 0 && t == 0) rowptr[Nn] = Ee;
}

__global__ __launch_bounds__(256) void scatter_fill(
    const int* __restrict__ ei, int* __restrict__ cursor,
    int* __restrict__ col)
{
    const int e = blockIdx.x * 256 + threadIdx.x;
    if (e >= Ee) return;
    const int s = ei[e];
    const int d = ei[Ee + e];
    const int pos = atomicAdd(&cursor[d], 1);
    col[pos] = s;
}

// ---------------------------------------------------------------------------
// Pull aggregation: agg[r] = sum_{j in row r} h[col[j]].
// 16 lanes per row (float4 each), 16 rows per block.
// ---------------------------------------------------------------------------
__global__ __launch_bounds__(256) void gather_agg(
    const int* __restrict__ rowptr, const int* __restrict__ col,
    const float* __restrict__ h, float* __restrict__ agg)
{
    const int r = blockIdx.x * 16 + (threadIdx.x >> 4);
    if (r >= Nn) return;
    const int q = threadIdx.x & 15;
    const int beg = rowptr[r];
    const int end = rowptr[r + 1];
    float4 acc = make_float4(0.f, 0.f, 0.f, 0.f);
    for (int j = beg; j < end; j++) {
        const int s = col[j];
        const float4 v = *(const float4*)(h + (size_t)s * 64 + q * 4);
        acc.x += v.x; acc.y += v.y; acc.z += v.z; acc.w += v.w;
    }
    *(float4*)(agg + (size_t)r * 64 + q * 4) = acc;
}

// Compute scale/shift from stats, then zero stats for the next layer.
__global__ void bn_finalize(
    float* __restrict__ stats, const float* __restrict__ gamma,
    const float* __restrict__ beta, float* __restrict__ sc, int layer)
{
    const int c = threadIdx.x; // 64 threads, 1 block
    const float mean = stats[c] * (1.0f / Nn);
    const float var = stats[64 + c] * (1.0f / Nn) - mean * mean;
    const float scale = gamma[layer * 64 + c] * rsqrtf(var + 1e-5f);
    sc[c] = scale;
    sc[64 + c] = beta[layer * 64 + c] - mean * scale;
    stats[c] = 0.f;
    stats[64 + c] = 0.f;
}

__device__ inline int lower_bound_i(const int* __restrict__ a, int n, int v)
{
    int lo = 0, hi = n;
    while (lo < hi) {
        const int m = (lo + hi) >> 1;
        if (a[m] < v) lo = m + 1; else hi = m;
    }
    return lo;
}

// ---------------------------------------------------------------------------
// Apply BN in place and accumulate per-graph pooled sums (batch sorted).
// 4 blocks per graph; one atomicAdd per column per block into pooled.
// ---------------------------------------------------------------------------
__global__ __launch_bounds__(256) void bn_apply_pool(
    float* __restrict__ z, const int* __restrict__ batch,
    const float* __restrict__ sc, float* __restrict__ pooled, int layer)
{
    const int g = blockIdx.x >> 2;
    const int sub = blockIdx.x & 3;
    const int lo = lower_bound_i(batch, Nn, g);
    const int hi = lower_bound_i(batch, Nn, g + 1);
    const int t = threadIdx.x;
    const int col = t & 63;
    const int rg = (t >> 6) + sub * 4; // 0..15
    const float scale = sc[col];
    const float shift = sc[64 + col];
    float acc = 0.f;
    for (int row = lo + rg; row < hi; row += 16) {
        float v = z[(size_t)row * 64 + col];
        v = fmaf(scale, v, shift);
        z[(size_t)row * 64 + col] = v;
        acc += v;
    }
    __shared__ float red[4][64];
    red[t >> 6][col] = acc;
    __syncthreads();
    if ((t >> 6) == 0) {
        const float tot = red[0][col] + red[1][col] + red[2][col] + red[3][col];
        atomicAdd(&pooled[g * PDim + layer * 64 + col], tot);
    }
}

// ---------------------------------------------------------------------------
// Proj head GEMM: (128,320)@(320,320)+b. One thread per output element.
// ---------------------------------------------------------------------------
template<bool RELU>
__global__ __launch_bounds__(256) void proj(
    const float* __restrict__ X, const float* __restrict__ W,
    const float* __restrict__ bias, float* __restrict__ Y)
{
    const int idx = blockIdx.x * 256 + threadIdx.x; // 40960 exact
    const int r = idx / PDim;
    const int c = idx - r * PDim;
    float acc = bias[c];
    #pragma unroll 8
    for (int k = 0; k < PDim; k++)
        acc = fmaf(X[r * PDim + k], W[k * PDim + c], acc);
    if constexpr (RELU) acc = fmaxf(acc, 0.f);
    Y[idx] = acc;
}

// ---------------------------------------------------------------------------
// Row-wise l2 normalize.
// ---------------------------------------------------------------------------
__global__ __launch_bounds__(64) void l2norm_rows(
    const float* __restrict__ X, float* __restrict__ out)
{
    const int r = blockIdx.x;
    const int l = threadIdx.x;
    float v[5];
    float s = 0.f;
    #pragma unroll
    for (int i = 0; i < 5; i++) {
        v[i] = X[r * PDim + i * 64 + l];
        s += v[i] * v[i];
    }
    #pragma unroll
    for (int off = 32; off > 0; off >>= 1) s += __shfl_down(s, off);
    s = __shfl(s, 0);
    const float d = fmaxf(sqrtf(s), 1e-12f);
    #pragma unroll
    for (int i = 0; i < 5; i++)
        out[r * PDim + i * 64 + l] = v[i] / d;
}

// ---------------------------------------------------------------------------
extern "C" void kernel_launch(void* const* d_in, const int* in_sizes, int n_in,
                              void* d_out, int out_size, void* d_ws, size_t ws_size,
                              hipStream_t stream)
{
    const float* x     = (const float*)d_in[0];
    const int*   ei    = (const int*)d_in[1];
    const int*   batch = (const int*)d_in[2];
    const float* Ws    = (const float*)d_in[3];
    const float* bs    = (const float*)d_in[4];
    const float* W1    = (const float*)d_in[5];
    const float* b1    = (const float*)d_in[6];
    const float* W2    = (const float*)d_in[7];
    const float* b2    = (const float*)d_in[8];
    const float* gamma = (const float*)d_in[9];
    const float* beta  = (const float*)d_in[10];
    const float* Wp1   = (const float*)d_in[11];
    const float* bp1   = (const float*)d_in[12];
    const float* Wp2   = (const float*)d_in[13];
    const float* bp2   = (const float*)d_in[14];
    float* out = (float*)d_out;

    float* A      = (float*)d_ws;                 // h        (N*64)
    float* B      = A + (size_t)Nn * 64;          // agg/z1/y (N*64)
    float* pooled = B + (size_t)Nn * 64;          // (G,320)
    float* ytmp   = pooled + (size_t)Gg * PDim;   // (G,320)
    float* stats  = ytmp + (size_t)Gg * PDim;     // 128 floats
    float* sc     = stats + 128;                  // 128 floats
    int*   deg    = (int*)(sc + 128);             // N ints
    int*   rowptr = deg + Nn;                     // N+1 ints
    int*   cursor = rowptr + Nn + 1;              // N ints
    int*   colidx = cursor + Nn;                  // E ints
    int*   bsums  = colidx + Ee;                  // SCAN_NBLK ints

    const int gemmGrid = (Nn + 63) / 64;
    const int edgeGrid = (Ee + 255) / 256;

    hipMemsetAsync(stats, 0, 128 * sizeof(float), stream);
    hipMemsetAsync(deg, 0, Nn * sizeof(int), stream);
    hipMemsetAsync(pooled, 0, (size_t)Gg * PDim * sizeof(float), stream);

    // CSR build (once per launch)
    count_deg<<<edgeGrid, 256, 0, stream>>>(ei, deg);
    deg_block_reduce<<<SCAN_NBLK, 256, 0, stream>>>(deg, bsums);
    scan_blocksums<<<1, 128, 0, stream>>>(bsums);
    deg_scan_scatter<<<SCAN_NBLK, 256, 0, stream>>>(deg, bsums, rowptr, cursor);
    scatter_fill<<<edgeGrid, 256, 0, stream>>>(ei, cursor, colidx);

    // encoder: A = x @ Ws + bs
    gemm64<false, false, false><<<gemmGrid, 256, 0, stream>>>(
        x, nullptr, Ws, bs, A, nullptr, Nn);

    for (int l = 0; l < Ll; l++) {
        gather_agg<<<(Nn + 15) / 16, 256, 0, stream>>>(rowptr, colidx, A, B);
        // z1 = relu((A+B)@W1+b1) -> B
        gemm64<true, true, false><<<gemmGrid, 256, 0, stream>>>(
            A, B, W1 + (size_t)l * 4096, b1 + (size_t)l * 64, B, nullptr, Nn);
        // z2 = relu(B@W2+b2) -> A, with fused BN stats
        gemm64<false, true, true><<<gemmGrid, 256, 0, stream>>>(
            B, nullptr, W2 + (size_t)l * 4096, b2 + (size_t)l * 64, A, stats, Nn);
        bn_finalize<<<1, 64, 0, stream>>>(stats, gamma, beta, sc, l);
        bn_apply_pool<<<Gg * 4, 256, 0, stream>>>(A, batch, sc, pooled, l);
    }

    // proj head
    proj<true><<<160, 256, 0, stream>>>(pooled, Wp1, bp1, ytmp);
    proj<false><<<160, 256, 0, stream>>>(ytmp, Wp2, bp2, B);

    l2norm_rows<<<Gg, 64, 0, stream>>>(B, out);                  // out0
    l2norm_rows<<<Gg, 64, 0, stream>>>(pooled, out + Gg * PDim); // out1
}

// Round 6
// 869.064 us; speedup vs baseline: 6.7705x; 1.1684x over previous
//
#include <hip/hip_runtime.h>
#include <hip/hip_bf16.h>
#include <hip/hip_fp16.h>

constexpr int Nn = 100000;
constexpr int Ee = 1200000;
constexpr int Ll = 5;
constexpr int Gg = 128;
constexpr int PDim = 320; // L*D

typedef short short8 __attribute__((ext_vector_type(8)));
typedef float f32x4 __attribute__((ext_vector_type(4)));

union U4S8 { uint4 u; short8 s; };

__device__ inline float bfl(uint u) { return __uint_as_float(u << 16); }
__device__ inline float bfh(uint u) { return __uint_as_float(u & 0xffff0000u); }
__device__ inline ushort f2bf(float f) {
    const uint u = __float_as_uint(f);
    return (ushort)((u + 0x7fffu + ((u >> 16) & 1u)) >> 16);
}
__device__ inline uint pack2(float lo, float hi) {
    return (uint)f2bf(lo) | ((uint)f2bf(hi) << 16);
}
// fp16 helpers (RTNE via v_cvt)
__device__ inline ushort f2h(float f) {
    const __half h = __float2half(f);
    return *(const ushort*)&h;
}
__device__ inline uint pack2h(float lo, float hi) {
    return (uint)f2h(lo) | ((uint)f2h(hi) << 16);
}
__device__ inline float h2f_lo(uint u) {
    const ushort s = (ushort)(u & 0xffffu);
    return __half2float(*(const __half*)&s);
}
__device__ inline float h2f_hi(uint u) {
    const ushort s = (ushort)(u >> 16);
    return __half2float(*(const __half*)&s);
}
// split x0,x1 into packed bf16 hi word + bf16 lo (residual) word
__device__ inline void split2(float x0, float x1, uint& hi, uint& lo) {
    const ushort h0 = f2bf(x0), h1 = f2bf(x1);
    hi = (uint)h0 | ((uint)h1 << 16);
    const float r0 = x0 - __uint_as_float((uint)h0 << 16);
    const float r1 = x1 - __uint_as_float((uint)h1 << 16);
    lo = pack2(r0, r1);
}

// ---------------------------------------------------------------------------
// Weight conversion: 11 64x64 f32 matrices -> TRANSPOSED bf16 hi/lo pair.
// Block m: 0=Ws, 1..5=W1[m-1], 6..10=W2[m-6].
// ---------------------------------------------------------------------------
__global__ __launch_bounds__(256) void conv_weights(
    const float* __restrict__ Ws, const float* __restrict__ W1,
    const float* __restrict__ W2, ushort* __restrict__ WThi,
    ushort* __restrict__ WTlo)
{
    const int m = blockIdx.x;
    const float* src = (m == 0) ? Ws
                     : (m <= 5) ? W1 + (size_t)(m - 1) * 4096
                                : W2 + (size_t)(m - 6) * 4096;
    ushort* dh = WThi + (size_t)m * 4096;
    ushort* dl = WTlo + (size_t)m * 4096;
    const int t = threadIdx.x;
    const int col = t & 63;
    const int k0 = (t >> 6) * 16;
    #pragma unroll
    for (int i = 0; i < 16; i++) {
        const int k = k0 + i;
        const float w = src[k * 64 + col];
        const ushort h = f2bf(w);
        dh[col * 64 + k] = h;
        dl[col * 64 + k] = f2bf(w - __uint_as_float((uint)h << 16));
    }
}

// ---------------------------------------------------------------------------
// Split-bf16 MFMA GEMM: Y = act(A (+A2) @ W + b), f32 in / f32 out.
// acc += Alo*Whi + Ahi*Wlo + Ahi*Whi (3 MFMA, f32-grade result).
// Block 256 = 4 waves; wave w owns rows blk*64+w*16..+16, all 64 cols.
// AMODE: 0 = A1 only; 1 = A1 + A2 (GIN sum).
// STATS: fused per-column sum/sumsq into stats[0:128].
// SHADOW: also write fp16 copy of output (for gather).
// ---------------------------------------------------------------------------
template<int AMODE, bool RELU, bool STATS, bool SHADOW>
__global__ __launch_bounds__(256) void gemm_mfma(
    const float* __restrict__ A1, const float* __restrict__ A2,
    const ushort* __restrict__ WThi, const ushort* __restrict__ WTlo,
    const float* __restrict__ bias, float* __restrict__ Y,
    ushort* __restrict__ Ys, float* __restrict__ stats)
{
    const int t = threadIdx.x;
    const int w = t >> 6;
    const int l = t & 63;
    const int lr = l & 15;   // A-row / B-col within tile
    const int lk = l >> 4;   // k-group (8 elems each)

    // B fragments: col = nt*16+lr, k = c*32 + lk*8 (contiguous in WT)
    short8 bHi[4][2], bLo[4][2];
    #pragma unroll
    for (int nt = 0; nt < 4; nt++)
        #pragma unroll
        for (int c = 0; c < 2; c++) {
            const int off = (nt * 16 + lr) * 64 + c * 32 + lk * 8;
            U4S8 uh, ul;
            uh.u = *(const uint4*)(WThi + off);
            ul.u = *(const uint4*)(WTlo + off);
            bHi[nt][c] = uh.s;
            bLo[nt][c] = ul.s;
        }

    // A fragments (NO early return: MFMA is wave-collective)
    const int arow = blockIdx.x * 64 + w * 16 + lr;
    short8 aHi[2], aLo[2];
    if (arow < Nn) {
        #pragma unroll
        for (int c = 0; c < 2; c++) {
            const int koff = c * 32 + lk * 8;
            const float* p1 = A1 + (size_t)arow * 64 + koff;
            float v[8];
            {
                const float4 v0 = *(const float4*)p1;
                const float4 v1 = *(const float4*)(p1 + 4);
                v[0] = v0.x; v[1] = v0.y; v[2] = v0.z; v[3] = v0.w;
                v[4] = v1.x; v[5] = v1.y; v[6] = v1.z; v[7] = v1.w;
            }
            if constexpr (AMODE == 1) {
                const float* p2 = A2 + (size_t)arow * 64 + koff;
                const float4 u0 = *(const float4*)p2;
                const float4 u1 = *(const float4*)(p2 + 4);
                v[0] += u0.x; v[1] += u0.y; v[2] += u0.z; v[3] += u0.w;
                v[4] += u1.x; v[5] += u1.y; v[6] += u1.z; v[7] += u1.w;
            }
            U4S8 rh, rl;
            uint* ph = (uint*)&rh.u;
            uint* pl = (uint*)&rl.u;
            #pragma unroll
            for (int i = 0; i < 4; i++)
                split2(v[2 * i], v[2 * i + 1], ph[i], pl[i]);
            aHi[c] = rh.s;
            aLo[c] = rl.s;
        }
    } else {
        U4S8 z; z.u = make_uint4(0, 0, 0, 0);
        aHi[0] = aHi[1] = z.s;
        aLo[0] = aLo[1] = z.s;
    }

    f32x4 acc[4] = {};
    #pragma unroll
    for (int nt = 0; nt < 4; nt++)
        #pragma unroll
        for (int c = 0; c < 2; c++) {
            acc[nt] = __builtin_amdgcn_mfma_f32_16x16x32_bf16(
                aLo[c], bHi[nt][c], acc[nt], 0, 0, 0);
            acc[nt] = __builtin_amdgcn_mfma_f32_16x16x32_bf16(
                aHi[c], bLo[nt][c], acc[nt], 0, 0, 0);
            acc[nt] = __builtin_amdgcn_mfma_f32_16x16x32_bf16(
                aHi[c], bHi[nt][c], acc[nt], 0, 0, 0);
        }

    // Epilogue: C/D layout col=lane&15, row=(lane>>4)*4+reg  [m89]
    float s[4], s2[4];
    #pragma unroll
    for (int nt = 0; nt < 4; nt++) {
        const int ccol = nt * 16 + lr;
        const float bb = bias[ccol];
        s[nt] = 0.f; s2[nt] = 0.f;
        #pragma unroll
        for (int j = 0; j < 4; j++) {
            const int crow = blockIdx.x * 64 + w * 16 + lk * 4 + j;
            if (crow < Nn) {
                float v = acc[nt][j] + bb;
                if constexpr (RELU) v = fmaxf(v, 0.f);
                Y[(size_t)crow * 64 + ccol] = v;
                if constexpr (SHADOW) Ys[(size_t)crow * 64 + ccol] = f2h(v);
                if constexpr (STATS) { s[nt] += v; s2[nt] += v * v; }
            }
        }
    }

    if constexpr (STATS) {
        #pragma unroll
        for (int nt = 0; nt < 4; nt++) {
            s[nt]  += __shfl_xor(s[nt], 16);  s[nt]  += __shfl_xor(s[nt], 32);
            s2[nt] += __shfl_xor(s2[nt], 16); s2[nt] += __shfl_xor(s2[nt], 32);
        }
        __shared__ float red[2][4][4][16]; // [s|s2][wave][nt][col16]
        if (l < 16) {
            #pragma unroll
            for (int nt = 0; nt < 4; nt++) {
                red[0][w][nt][l] = s[nt];
                red[1][w][nt][l] = s2[nt];
            }
        }
        __syncthreads();
        if (t < 64) { // column = (t>>4)*16 + (t&15) = t
            float ts = 0.f, ts2 = 0.f;
            #pragma unroll
            for (int wv = 0; wv < 4; wv++) {
                ts  += red[0][wv][t >> 4][t & 15];
                ts2 += red[1][wv][t >> 4][t & 15];
            }
            atomicAdd(&stats[t], ts);
            atomicAdd(&stats[64 + t], ts2);
        }
    }
}

// ---------------------------------------------------------------------------
// CSR build: degree count -> device-wide scan (3 phases) -> scatter-fill
// ---------------------------------------------------------------------------
__global__ __launch_bounds__(256) void count_deg(
    const int* __restrict__ ei, int* __restrict__ deg)
{
    const int e = blockIdx.x * 256 + threadIdx.x;
    if (e < Ee) atomicAdd(&deg[ei[Ee + e]], 1); // dst
}

constexpr int SCAN_TILE = 1024;
constexpr int SCAN_NBLK = (Nn + SCAN_TILE - 1) / SCAN_TILE; // 98

__global__ __launch_bounds__(256) void deg_block_reduce(
    const int* __restrict__ deg, int* __restrict__ blockSums)
{
    const int t = threadIdx.x;
    const int base = blockIdx.x * SCAN_TILE + t * 4;
    int s = 0;
    if (base + 4 <= Nn) {
        const int4 v = *(const int4*)(deg + base);
        s = v.x + v.y + v.z + v.w;
    } else {
        for (int i = 0; i < 4; i++) if (base + i < Nn) s += deg[base + i];
    }
    __shared__ int sh[256];
    sh[t] = s;
    __syncthreads();
    for (int off = 128; off > 0; off >>= 1) {
        if (t < off) sh[t] += sh[t + off];
        __syncthreads();
    }
    if (t == 0) blockSums[blockIdx.x] = sh[0];
}

__global__ __launch_bounds__(128) void scan_blocksums(int* __restrict__ blockSums)
{
    __shared__ int sh[128];
    const int t = threadIdx.x;
    const int v = (t < SCAN_NBLK) ? blockSums[t] : 0;
    sh[t] = v;
    __syncthreads();
    for (int off = 1; off < 128; off <<= 1) {
        const int u = (t >= off) ? sh[t - off] : 0;
        __syncthreads();
        sh[t] += u;
        __syncthreads();
    }
    if (t < SCAN_NBLK) blockSums[t] = sh[t] - v; // exclusive
}

__global__ __launch_bounds__(256) void deg_scan_scatter(
    const int* __restrict__ deg, const int* __restrict__ blockSums,
    int* __restrict__ rowptr, int* __restrict__ cursor)
{
    const int t = threadIdx.x;
    const int base = blockIdx.x * SCAN_TILE + t * 4;
    int v[4];
    int s = 0;
    #pragma unroll
    for (int i = 0; i < 4; i++) {
        const int idx = base + i;
        v[i] = (idx < Nn) ? deg[idx] : 0;
        s += v[i];
    }
    __shared__ int sh[256];
    sh[t] = s;
    __syncthreads();
    for (int off = 1; off < 256; off <<= 1) {
        const int u = (t >= off) ? sh[t - off] : 0;
        __syncthreads();
        sh[t] += u;
        __syncthreads();
    }
    int excl = sh[t] - s + blockSums[blockIdx.x];
    #pragma unroll
    for (int i = 0; i < 4; i++) {
        const int idx = base + i;
        if (idx < Nn) {
            rowptr[idx] = excl;
            cursor[idx] = excl;
            excl += v[i];
        }
    }
    if (blockIdx.x == 0 && t == 0) rowptr[Nn] = Ee;
}

__global__ __launch_bounds__(256) void scatter_fill(
    const int* __restrict__ ei, int* __restrict__ cursor, int* __restrict__ col)
{
    const int e = blockIdx.x * 256 + threadIdx.x;
    if (e >= Ee) return;
    const int s = ei[e];
    const int d = ei[Ee + e];
    const int pos = atomicAdd(&cursor[d], 1);
    col[pos] = s;
}

// ---------------------------------------------------------------------------
// Pull aggregation: agg[r] (f32) = sum_{j in row r} hs[col[j]] (fp16 shadow).
// 8 lanes per row (uint4 = 8 fp16 each), 32 rows per block. Grid exact.
// ---------------------------------------------------------------------------
__global__ __launch_bounds__(256) void gather_agg_h(
    const int* __restrict__ rowptr, const int* __restrict__ col,
    const ushort* __restrict__ hs, float* __restrict__ agg)
{
    const int r = blockIdx.x * 32 + (threadIdx.x >> 3);
    const int q = threadIdx.x & 7;
    const int beg = rowptr[r], end = rowptr[r + 1];
    float a[8] = {};
    for (int j = beg; j < end; j++) {
        const int s = col[j];
        const uint4 v = *(const uint4*)(hs + (size_t)s * 64 + q * 8);
        a[0] += h2f_lo(v.x); a[1] += h2f_hi(v.x);
        a[2] += h2f_lo(v.y); a[3] += h2f_hi(v.y);
        a[4] += h2f_lo(v.z); a[5] += h2f_hi(v.z);
        a[6] += h2f_lo(v.w); a[7] += h2f_hi(v.w);
    }
    float* o = agg + (size_t)r * 64 + q * 8;
    *(float4*)o       = make_float4(a[0], a[1], a[2], a[3]);
    *(float4*)(o + 4) = make_float4(a[4], a[5], a[6], a[7]);
}

// Compute scale/shift from stats, then zero stats for the next layer.
__global__ void bn_finalize(
    float* __restrict__ stats, const float* __restrict__ gamma,
    const float* __restrict__ beta, float* __restrict__ sc, int layer)
{
    const int c = threadIdx.x; // 64 threads, 1 block
    const float mean = stats[c] * (1.0f / Nn);
    const float var = stats[64 + c] * (1.0f / Nn) - mean * mean;
    const float scale = gamma[layer * 64 + c] * rsqrtf(var + 1e-5f);
    sc[c] = scale;
    sc[64 + c] = beta[layer * 64 + c] - mean * scale;
    stats[c] = 0.f;
    stats[64 + c] = 0.f;
}

__device__ inline int lower_bound_i(const int* __restrict__ a, int n, int v)
{
    int lo = 0, hi = n;
    while (lo < hi) {
        const int m = (lo + hi) >> 1;
        if (a[m] < v) lo = m + 1; else hi = m;
    }
    return lo;
}

// ---------------------------------------------------------------------------
// Apply BN in place (f32), write fp16 shadow, accumulate per-graph pooled
// sums (f32). 8 blocks per graph; batch is sorted.
// ---------------------------------------------------------------------------
__global__ __launch_bounds__(256) void bn_apply_pool(
    float* __restrict__ z, ushort* __restrict__ zs,
    const int* __restrict__ batch, const float* __restrict__ sc,
    float* __restrict__ pooled, int layer)
{
    const int g = blockIdx.x >> 3;
    const int sub = blockIdx.x & 7;
    const int lo = lower_bound_i(batch, Nn, g);
    const int hi = lower_bound_i(batch, Nn, g + 1);
    const int t = threadIdx.x;
    const int cq = t & 15;                 // cols cq*4 .. +3
    const int rg = (t >> 4) + sub * 16;    // 0..127
    float scl[4], sft[4], acc[4] = {};
    #pragma unroll
    for (int i = 0; i < 4; i++) {
        scl[i] = sc[cq * 4 + i];
        sft[i] = sc[64 + cq * 4 + i];
    }
    for (int row = lo + rg; row < hi; row += 128) {
        float4 v = *(float4*)(z + (size_t)row * 64 + cq * 4);
        v.x = fmaf(scl[0], v.x, sft[0]);
        v.y = fmaf(scl[1], v.y, sft[1]);
        v.z = fmaf(scl[2], v.z, sft[2]);
        v.w = fmaf(scl[3], v.w, sft[3]);
        *(float4*)(z + (size_t)row * 64 + cq * 4) = v;
        uint2 p;
        p.x = pack2h(v.x, v.y);
        p.y = pack2h(v.z, v.w);
        *(uint2*)(zs + (size_t)row * 64 + cq * 4) = p;
        acc[0] += v.x; acc[1] += v.y; acc[2] += v.z; acc[3] += v.w;
    }
    __shared__ float red[16][16][4];
    #pragma unroll
    for (int i = 0; i < 4; i++) red[t >> 4][cq][i] = acc[i];
    __syncthreads();
    if (t < 64) {
        const int c2 = t >> 2, j = t & 3;
        float s = 0.f;
        #pragma unroll
        for (int r = 0; r < 16; r++) s += red[r][c2][j];
        atomicAdd(&pooled[g * PDim + layer * 64 + c2 * 4 + j], s);
    }
}

// ---------------------------------------------------------------------------
// Proj head GEMM: (128,320)@(320,320)+b (f32, small).
// ---------------------------------------------------------------------------
template<bool RELU>
__global__ __launch_bounds__(256) void proj(
    const float* __restrict__ X, const float* __restrict__ W,
    const float* __restrict__ bias, float* __restrict__ Y)
{
    const int idx = blockIdx.x * 256 + threadIdx.x; // 40960 exact
    const int r = idx / PDim;
    const int c = idx - r * PDim;
    float acc = bias[c];
    #pragma unroll 8
    for (int k = 0; k < PDim; k++)
        acc = fmaf(X[r * PDim + k], W[k * PDim + c], acc);
    if constexpr (RELU) acc = fmaxf(acc, 0.f);
    Y[idx] = acc;
}

// ---------------------------------------------------------------------------
// Row-wise l2 normalize.
// ---------------------------------------------------------------------------
__global__ __launch_bounds__(64) void l2norm_rows(
    const float* __restrict__ X, float* __restrict__ out)
{
    const int r = blockIdx.x;
    const int l = threadIdx.x;
    float v[5];
    float s = 0.f;
    #pragma unroll
    for (int i = 0; i < 5; i++) {
        v[i] = X[r * PDim + i * 64 + l];
        s += v[i] * v[i];
    }
    #pragma unroll
    for (int off = 32; off > 0; off >>= 1) s += __shfl_down(s, off);
    s = __shfl(s, 0);
    const float d = fmaxf(sqrtf(s), 1e-12f);
    #pragma unroll
    for (int i = 0; i < 5; i++)
        out[r * PDim + i * 64 + l] = v[i] / d;
}

// ---------------------------------------------------------------------------
extern "C" void kernel_launch(void* const* d_in, const int* in_sizes, int n_in,
                              void* d_out, int out_size, void* d_ws, size_t ws_size,
                              hipStream_t stream)
{
    const float* x     = (const float*)d_in[0];
    const int*   ei    = (const int*)d_in[1];
    const int*   batch = (const int*)d_in[2];
    const float* Ws    = (const float*)d_in[3];
    const float* bs    = (const float*)d_in[4];
    const float* W1    = (const float*)d_in[5];
    const float* b1    = (const float*)d_in[6];
    const float* W2    = (const float*)d_in[7];
    const float* b2    = (const float*)d_in[8];
    const float* gamma = (const float*)d_in[9];
    const float* beta  = (const float*)d_in[10];
    const float* Wp1   = (const float*)d_in[11];
    const float* bp1   = (const float*)d_in[12];
    const float* Wp2   = (const float*)d_in[13];
    const float* bp2   = (const float*)d_in[14];
    float* out = (float*)d_out;

    // workspace (all segments 16B-aligned by construction)
    float*  Hf  = (float*)d_ws;                   // h f32 (N*64)      25.6MB
    float*  Gf  = Hf + (size_t)Nn * 64;           // agg f32           25.6MB
    float*  Zf  = Gf + (size_t)Nn * 64;           // z1 f32            25.6MB
    ushort* Hs  = (ushort*)(Zf + (size_t)Nn * 64);// h fp16 shadow     12.8MB
    ushort* WThi = Hs + (size_t)Nn * 64;          // 11*4096 bf16
    ushort* WTlo = WThi + 11 * 4096;
    float* pooled = (float*)(WTlo + 11 * 4096);   // (G,320)
    float* ytmp   = pooled + (size_t)Gg * PDim;
    float* ypro   = ytmp + (size_t)Gg * PDim;
    float* stats  = ypro + (size_t)Gg * PDim;     // 128
    float* sc     = stats + 128;                  // 128
    int* deg    = (int*)(sc + 128);               // N
    int* rowptr = deg + Nn;                       // N+1
    int* cursor = rowptr + Nn + 1;                // N
    int* colidx = cursor + Nn;                    // E
    int* bsums  = colidx + Ee;                    // 98

    const int gemmGrid = (Nn + 63) / 64;          // 1563
    const int edgeGrid = (Ee + 255) / 256;

    hipMemsetAsync(stats, 0, 128 * sizeof(float), stream);
    hipMemsetAsync(deg, 0, Nn * sizeof(int), stream);
    hipMemsetAsync(pooled, 0, (size_t)Gg * PDim * sizeof(float), stream);

    conv_weights<<<11, 256, 0, stream>>>(Ws, W1, W2, WThi, WTlo);

    // CSR build
    count_deg<<<edgeGrid, 256, 0, stream>>>(ei, deg);
    deg_block_reduce<<<SCAN_NBLK, 256, 0, stream>>>(deg, bsums);
    scan_blocksums<<<1, 128, 0, stream>>>(bsums);
    deg_scan_scatter<<<SCAN_NBLK, 256, 0, stream>>>(deg, bsums, rowptr, cursor);
    scatter_fill<<<edgeGrid, 256, 0, stream>>>(ei, cursor, colidx);

    // encoder: Hf = x @ Ws + bs (f32), Hs = fp16 shadow
    gemm_mfma<0, false, false, true><<<gemmGrid, 256, 0, stream>>>(
        x, nullptr, WThi, WTlo, bs, Hf, Hs, nullptr);

    for (int l = 0; l < Ll; l++) {
        gather_agg_h<<<Nn / 32, 256, 0, stream>>>(rowptr, colidx, Hs, Gf);
        // z1 = relu((h+agg)@W1+b1) -> Zf (f32)
        gemm_mfma<1, true, false, false><<<gemmGrid, 256, 0, stream>>>(
            Hf, Gf, WThi + (size_t)(1 + l) * 4096, WTlo + (size_t)(1 + l) * 4096,
            b1 + (size_t)l * 64, Zf, nullptr, nullptr);
        // z2 = relu(z1@W2+b2) -> Hf (f32), fused BN stats
        gemm_mfma<0, true, true, false><<<gemmGrid, 256, 0, stream>>>(
            Zf, nullptr, WThi + (size_t)(6 + l) * 4096, WTlo + (size_t)(6 + l) * 4096,
            b2 + (size_t)l * 64, Hf, nullptr, stats);
        bn_finalize<<<1, 64, 0, stream>>>(stats, gamma, beta, sc, l);
        bn_apply_pool<<<Gg * 8, 256, 0, stream>>>(Hf, Hs, batch, sc, pooled, l);
    }

    // proj head (f32)
    proj<true><<<160, 256, 0, stream>>>(pooled, Wp1, bp1, ytmp);
    proj<false><<<160, 256, 0, stream>>>(ytmp, Wp2, bp2, ypro);

    l2norm_rows<<<Gg, 64, 0, stream>>>(ypro, out);               // out0
    l2norm_rows<<<Gg, 64, 0, stream>>>(pooled, out + Gg * PDim); // out1
}